// Round 7
// baseline (240.386 us; speedup 1.0000x reference)
//
#include <hip/hip_runtime.h>
#include <math.h>

// sources: [4][32][512][512] fp32, kernels: [12][3][3] fp32, out: same as sources
// out_i = s_i - sum_j [ conv(s_j, kc_ij) + conv((s_j^0.5 * s_i)^(2/3), ki_ij) ]
//
// Identity: a = v^(1/3) => s = a^3, (s_j^0.5 * s_i)^(2/3) = a_j * a_i^2.
// Stage only a in LDS; conv is multiply/FMA only; edge sweep (0,1),(1,2),(2,3).
//
// ROUND-7: edge window columns via DPP, not LDS.
//   Round 4/6 read w0 (col 4tx+3) and w5 (col 4tx+8) as b32 -> all 64 lanes
//   on 8 banks (8-way, ~1.9K conflict-cyc/block, LDS pipe ~50us/CU = the
//   co-binding pipe). Round 6's b64 fix was silently narrowed back to b32 by
//   LLVM (dead-component elimination) -> identical counters. Now: w0/w5 are
//   the NEIGHBOR LANE's m.w/m.x -> v_mov_b32_dpp row_shr:1/row_shl:1 (16-lane
//   rows == tx groups, pure VALU). Lanes tx==0/15 patched from halo cols
//   3/68 via one exec-masked b32 per channel-row, hoisted out of the loop.
//   Plus: carry shared channels (1,2) in registers across edges: b128 reads
//   18 -> 12 per thread. All values bit-identical to round 4.
//
// HISTORY (do not regress):
//  - launch_bounds (256,8)/(256,4): VGPR cap -> spills. WRITE_SIZE must stay
//    exactly 131072 KB; anything more is scratch traffic. Leave unbounded.
//  - scalar staging loads: Little's-law capped kernel at ~250 us. Keep
//    batched float4 staging (all 5 loads in flight before first use).
//  - 2 images/block + reg prefetch: net loss (occupancy + serial chain).
//  - partially-dead vector LDS loads get narrowed by the compiler; use DPP
//    or keep all components live.

#define NCH  4
#define NIMG 32
#define HH   512
#define WW   512

#define TW   64
#define TH   16
#define HTW  72            // LDS row stride (dwords); col k = global tile_x+k-4
#define HTH  18
#define NTASK (NCH * HTH)  // 72 row-channel staging tasks

#if __has_builtin(__builtin_amdgcn_exp2f)
#define EXP2(x) __builtin_amdgcn_exp2f(x)
#else
#define EXP2(x) exp2f(x)
#endif
#if __has_builtin(__builtin_amdgcn_logf)
#define LOG2(x) __builtin_amdgcn_logf(x)
#else
#define LOG2(x) __log2f(x)
#endif

__device__ __forceinline__ float cbrtfast(float v) {
    return EXP2(0.33333334f * LOG2(v));   // v=0 -> -inf -> 0 (correct zero-pad)
}

// DPP row shifts within 16-lane rows (== tx groups). Invalid lanes get old=0
// and are patched by cndmask from the halo registers.
__device__ __forceinline__ float dpp_shr1(float v) {   // lane tx gets tx-1's v
    return __int_as_float(__builtin_amdgcn_update_dpp(
        0, __float_as_int(v), 0x111, 0xf, 0xf, false));
}
__device__ __forceinline__ float dpp_shl1(float v) {   // lane tx gets tx+1's v
    return __int_as_float(__builtin_amdgcn_update_dpp(
        0, __float_as_int(v), 0x101, 0xf, 0xf, false));
}

// One channel's conv inputs held in registers: 3 rows x 4 center cols + halo.
struct ChRows {
    float4 m[3];   // LDS cols tx4+4..tx4+7 = global cols tx4..tx4+3
    float  h[3];   // tx==0: LDS col 3 (left halo); tx==15: col 68 (right halo)
};

__device__ __forceinline__ void load_ch(const float (*S)[HTW],
                                        int ty, int tx, int tx4, ChRows& c) {
    #pragma unroll
    for (int r = 0; r < 3; ++r)
        c.m[r] = *(const float4*)&S[ty + r][tx4 + 4];   // 16B-aligned b128
    const bool e = (tx == 0) | (tx == 15);
    const int hcol = (tx == 0) ? 3 : 68;
    #pragma unroll
    for (int r = 0; r < 3; ++r)
        c.h[r] = e ? S[ty + r][hcol] : 0.f;             // 8 active lanes/wave
}

// Assemble the 6-wide window for row r: w1..w4 from m, w0/w5 via DPP+patch.
__device__ __forceinline__ void window6(const ChRows& c, int r, int tx, float w[6]) {
    const float4 m = c.m[r];
    const float s0 = dpp_shr1(m.w);
    const float s5 = dpp_shl1(m.x);
    w[0] = (tx == 0)  ? c.h[r] : s0;
    w[1] = m.x; w[2] = m.y; w[3] = m.z; w[4] = m.w;
    w[5] = (tx == 15) ? c.h[r] : s5;
}

// Edge between channels x and y (a-values in X, Y).
//   accX += conv(a_y^3, ker[KCX]) + conv(a_x^2 * a_y, ker[KIX])   (i=x, j=y)
//   accY += conv(a_x^3, ker[KCY]) + conv(a_y^2 * a_x, ker[KIY])   (i=y, j=x)
template<int KCX, int KIX, int KCY, int KIY>
__device__ __forceinline__ void edge_conv(
    const ChRows& X, const ChRows& Y, int tx,
    const float* __restrict__ ker, float accX[4], float accY[4])
{
    #pragma unroll
    for (int r = 0; r < 3; ++r) {
        float ax[6], ay[6];
        window6(X, r, tx, ax);
        window6(Y, r, tx, ay);

        float ay2[6];
        #pragma unroll
        for (int q = 0; q < 6; ++q) ay2[q] = ay[q] * ay[q];

        // i=x (neighbor j=y): raw_y = ay^3, inter = ax^2 * ay
        {
            float w[6], t[6];
            #pragma unroll
            for (int q = 0; q < 6; ++q) {
                w[q] = ay2[q] * ay[q];
                t[q] = (ax[q] * ax[q]) * ay[q];
            }
            #pragma unroll
            for (int q = 0; q < 4; ++q) {
                float s = accX[q];
                #pragma unroll
                for (int dx = 0; dx < 3; ++dx) {
                    s = fmaf(w[q + dx], ker[KCX * 9 + r * 3 + dx], s);
                    s = fmaf(t[q + dx], ker[KIX * 9 + r * 3 + dx], s);
                }
                accX[q] = s;
            }
        }
        // i=y (neighbor j=x): raw_x = ax^3, inter = ay^2 * ax
        {
            float w[6], t[6];
            #pragma unroll
            for (int q = 0; q < 6; ++q) {
                w[q] = (ax[q] * ax[q]) * ax[q];
                t[q] = ay2[q] * ax[q];
            }
            #pragma unroll
            for (int q = 0; q < 4; ++q) {
                float s = accY[q];
                #pragma unroll
                for (int dx = 0; dx < 3; ++dx) {
                    s = fmaf(w[q + dx], ker[KCY * 9 + r * 3 + dx], s);
                    s = fmaf(t[q + dx], ker[KIY * 9 + r * 3 + dx], s);
                }
                accY[q] = s;
            }
        }
    }
}

// out = center^3 - bleed; center = m[1] (global cols tx4..tx4+3, row ty).
__device__ __forceinline__ void store_out(float* __restrict__ p,
                                          const float4 c, const float a[4]) {
    float4 o;
    o.x = c.x * c.x * c.x - a[0];
    o.y = c.y * c.y * c.y - a[1];
    o.z = c.z * c.z * c.z - a[2];
    o.w = c.w * c.w * c.w - a[3];
    *(float4*)p = o;
}

__global__ __launch_bounds__(256) void bleed_kernel(
    const float* __restrict__ src,   // [4][32][512][512]
    const float* __restrict__ ker,   // [12][3][3]
    float* __restrict__ out)
{
    __shared__ __align__(16) float sA[NCH][HTH][HTW];  // a = v^(1/3)

    const int tid    = threadIdx.x;
    const int tx     = tid & 15;      // col group: cols 4*tx .. 4*tx+3
    const int ty     = tid >> 4;      // row 0..15
    const int tx4    = tx * 4;
    const int tile_x = blockIdx.x * TW;
    const int tile_y = blockIdx.y * TH;
    const int n      = blockIdx.z;    // image index

    const size_t plane = (size_t)HH * WW;

    // ---- stage a = v^(1/3), zero-padded halo; float4 loads, batched ----
    // 16 groups of 16 lanes; task t = (channel c = t/18, row = t%18).
    // Lane L loads float4 of global cols tile_x+4L..+3 -> LDS cols 4+4L..7+4L.
    // Lane 0 also loads left halo (-> LDS col 3), lane 1 right halo (-> col
    // 68). All 5 tasks' loads issued before any use (bytes-in-flight).
    {
        const int g = tid >> 4;
        const int L = tid & 15;
        float4 vv[5];
        float  hv[5];
        #pragma unroll
        for (int it = 0; it < 5; ++it) {
            const int t   = g + it * 16;
            const int c   = t / HTH;
            const int row = t - c * HTH;
            const int gy  = tile_y - 1 + row;
            float4 v = make_float4(0.f, 0.f, 0.f, 0.f);
            float  h = 0.f;
            if (t < NTASK && (unsigned)gy < HH) {
                const float* rp = src + ((size_t)c * NIMG + n) * plane
                                      + (size_t)gy * WW;
                v = *(const float4*)(rp + tile_x + 4 * L);
                if (L == 0 && tile_x > 0)       h = rp[tile_x - 1];
                if (L == 1 && tile_x + TW < WW) h = rp[tile_x + TW];
            }
            vv[it] = v;
            hv[it] = h;
        }
        #pragma unroll
        for (int it = 0; it < 5; ++it) {
            const int t = g + it * 16;
            if (t < NTASK) {
                const int c   = t / HTH;
                const int row = t - c * HTH;
                float4 a;
                a.x = cbrtfast(vv[it].x);
                a.y = cbrtfast(vv[it].y);
                a.z = cbrtfast(vv[it].z);
                a.w = cbrtfast(vv[it].w);
                const float ah = cbrtfast(hv[it]);
                *(float4*)&sA[c][row][4 + 4 * L] = a;    // 16B-aligned ds_write
                if (L == 0) sA[c][row][3]  = ah;
                if (L == 1) sA[c][row][68] = ah;
            }
        }
    }
    __syncthreads();   // only barrier: everything after is read-only LDS

    const int gy  = tile_y + ty;
    const int gx0 = tile_x + tx4;
    float* outp = out + (size_t)n * plane + (size_t)gy * WW + gx0;
    const size_t cstride = (size_t)NIMG * plane;

    float accL[4] = {0.f, 0.f, 0.f, 0.f};
    float accH[4] = {0.f, 0.f, 0.f, 0.f};

    ChRows A, B;
    load_ch(sA[0], ty, tx, tx4, A);          // A = ch0
    load_ch(sA[1], ty, tx, tx4, B);          // B = ch1

    // edge (0,1): i=0 gets kc=0,ki=1 ; i=1 gets kc=2,ki=3
    edge_conv<0, 1, 2, 3>(A, B, tx, ker, accL, accH);
    store_out(outp, A.m[1], accL);                    // channel 0 complete

    #pragma unroll
    for (int q = 0; q < 4; ++q) { accL[q] = accH[q]; accH[q] = 0.f; }
    load_ch(sA[2], ty, tx, tx4, A);          // A = ch2 (B=ch1 carried)

    // edge (1,2): i=1 gets kc=4,ki=5 ; i=2 gets kc=6,ki=7
    edge_conv<4, 5, 6, 7>(B, A, tx, ker, accL, accH);
    store_out(outp + cstride, B.m[1], accL);          // channel 1 complete

    #pragma unroll
    for (int q = 0; q < 4; ++q) { accL[q] = accH[q]; accH[q] = 0.f; }
    load_ch(sA[3], ty, tx, tx4, B);          // B = ch3 (A=ch2 carried)

    // edge (2,3): i=2 gets kc=8,ki=9 ; i=3 gets kc=10,ki=11
    edge_conv<8, 9, 10, 11>(A, B, tx, ker, accL, accH);
    store_out(outp + 2 * cstride, A.m[1], accL);      // channel 2 complete
    store_out(outp + 3 * cstride, B.m[1], accH);      // channel 3 complete
}

extern "C" void kernel_launch(void* const* d_in, const int* in_sizes, int n_in,
                              void* d_out, int out_size, void* d_ws, size_t ws_size,
                              hipStream_t stream) {
    const float* src = (const float*)d_in[0];
    const float* ker = (const float*)d_in[1];
    float* out = (float*)d_out;

    dim3 grid(WW / TW, HH / TH, NIMG);   // (8, 32, 32) = 8192 blocks
    dim3 block(256);
    bleed_kernel<<<grid, block, 0, stream>>>(src, ker, out);
}